// Round 2
// baseline (7747.680 us; speedup 1.0000x reference)
//
#include <hip/hip_runtime.h>
#include <hip/hip_bf16.h>
#include <math.h>

#define BB 2
#define NN 2048
#define MM 2048
#define DIMD 1024
#define HH 8
#define DHD 64
#define INNERD 512
#define FFD 8192
#define SCALE_QK 0.125f

typedef __hip_bfloat16 bf16;

__device__ __forceinline__ float cvt(float v) { return v; }
__device__ __forceinline__ float cvt(bf16 v) { return __bfloat162float(v); }
__device__ __forceinline__ void stc(float* p, float v) { *p = v; }
__device__ __forceinline__ void stc(bf16* p, float v) { *p = __float2bfloat16(v); }

// ---------------- reductions ----------------
__device__ __forceinline__ float block_reduce_sum(float v) {
    __shared__ float sh[4];
    int tid = threadIdx.x;
#pragma unroll
    for (int off = 32; off > 0; off >>= 1) v += __shfl_down(v, off, 64);
    __syncthreads();
    if ((tid & 63) == 0) sh[tid >> 6] = v;
    __syncthreads();
    return sh[0] + sh[1] + sh[2] + sh[3];
}

__device__ __forceinline__ float block_reduce_max(float v) {
    __shared__ float sh[4];
    int tid = threadIdx.x;
#pragma unroll
    for (int off = 32; off > 0; off >>= 1) v = fmaxf(v, __shfl_down(v, off, 64));
    __syncthreads();
    if ((tid & 63) == 0) sh[tid >> 6] = v;
    __syncthreads();
    return fmaxf(fmaxf(sh[0], sh[1]), fmaxf(sh[2], sh[3]));
}

// ---------------- layernorm: fp32 in -> bf16 out ----------------
__global__ __launch_bounds__(256) void layernorm_k(const float* __restrict__ in,
                                                   bf16* __restrict__ out,
                                                   const float* __restrict__ g,
                                                   const float* __restrict__ b) {
    long long row = blockIdx.x;
    const float* xr = in + row * DIMD;
    bf16* yr = out + row * DIMD;
    int tid = threadIdx.x;
    float s = 0.f;
    for (int i = tid; i < DIMD; i += 256) s += xr[i];
    float mean = block_reduce_sum(s) * (1.0f / DIMD);
    float s2 = 0.f;
    for (int i = tid; i < DIMD; i += 256) { float d = xr[i] - mean; s2 += d * d; }
    float var = block_reduce_sum(s2) * (1.0f / DIMD);
    float inv = 1.0f / sqrtf(var + 1e-5f);
    for (int i = tid; i < DIMD; i += 256)
        yr[i] = __float2bfloat16((xr[i] - mean) * inv * g[i] + b[i]);
}

// ---------------- row softmax stats over j (last dim) ----------------
__global__ __launch_bounds__(256) void rowstats_k(const bf16* __restrict__ sim,
                                                  float* __restrict__ mr,
                                                  float* __restrict__ lr) {
    long long row = blockIdx.x;  // h*NN + i
    const bf16* xr = sim + row * MM;
    int tid = threadIdx.x;
    float m = -3.4e38f;
    for (int j = tid; j < MM; j += 256) m = fmaxf(m, cvt(xr[j]));
    m = block_reduce_max(m);
    float s = 0.f;
    for (int j = tid; j < MM; j += 256) s += expf(cvt(xr[j]) - m);
    s = block_reduce_sum(s);
    if (tid == 0) { mr[row] = m; lr[row] = s; }
}

// ---------------- col softmax stats over i ----------------
__global__ __launch_bounds__(256) void colstats_k(const bf16* __restrict__ sim,
                                                  float* __restrict__ mc,
                                                  float* __restrict__ lc) {
    int h = blockIdx.y;
    int j = blockIdx.x * 256 + threadIdx.x;
    const bf16* base = sim + (long long)h * NN * MM;
    float m = -3.4e38f, s = 0.f;
    for (int i = 0; i < NN; i++) {
        float v = cvt(base[(long long)i * MM + j]);
        float nm = fmaxf(m, v);
        s = s * expf(m - nm) + expf(v - nm);
        m = nm;
    }
    mc[h * MM + j] = m;
    lc[h * MM + j] = s;
}

// ---------------- fused normalize + talking-heads mix, in place ----------------
// stat index: row mode -> h*NN + (idx>>11);  col mode -> h*MM + (idx&2047)
template <bool COLMODE>
__global__ __launch_bounds__(256) void mixnorm_k(bf16* __restrict__ sim,
                                                 const float* __restrict__ w,
                                                 const float* __restrict__ mm_,
                                                 const float* __restrict__ ll_) {
    __shared__ float ws_[64];
    if (threadIdx.x < 64) ws_[threadIdx.x] = w[threadIdx.x];
    __syncthreads();
    const long long NM = (long long)NN * MM;
    long long idx = (long long)blockIdx.x * 256 + threadIdx.x;
    int si = COLMODE ? (int)(idx & (MM - 1)) : (int)(idx >> 11);
    float p[HH];
#pragma unroll
    for (int h = 0; h < HH; h++) {
        int st = h * 2048 + si;
        p[h] = expf(cvt(sim[h * NM + idx]) - mm_[st]) * (1.0f / ll_[st]);
    }
#pragma unroll
    for (int g = 0; g < HH; g++) {
        float o = 0.f;
#pragma unroll
        for (int h = 0; h < HH; h++) o += ws_[g * 8 + h] * p[h];
        sim[g * NM + idx] = __float2bfloat16(o);
    }
}

// ---------------- generic tiled GEMM, fp32 accumulate ----------------
// A is bf16. B is BT (float weights from d_in, or bf16 from ws). C is CT.
// C[m,n] = alpha * sum_k A(m,k)*B(k,n) (+bias[n]) (+residual[m,n]) (->gelu)
// TA: A stored [k,m]; TB: B stored [n,k].
template <typename BT, typename CT, bool TA, bool TB>
__global__ __launch_bounds__(256) void gemm_k(
    const bf16* __restrict__ A, const BT* __restrict__ B, CT* __restrict__ C,
    int M, int N, int K, int lda, int ldb, int ldc,
    long long sA, long long sB, long long sC,
    float alpha, const float* __restrict__ bias,
    const float* __restrict__ residual, long long sR, int ldr, int gelu_flag) {
    constexpr int BM = 64, BN = 64, BK = 16;
    __shared__ float As[BK][BM + 1];
    __shared__ float Bs[BK][BN + 1];
    int batch = blockIdx.z;
    A += batch * sA;
    B += batch * sB;
    C += batch * sC;
    if (residual) residual += batch * sR;
    int m0 = blockIdx.y * BM;
    int n0 = blockIdx.x * BN;
    int tid = threadIdx.x;
    int tm = (tid / 16) * 4;
    int tn = (tid % 16) * 4;
    float acc[4][4] = {};
    for (int k0 = 0; k0 < K; k0 += BK) {
#pragma unroll
        for (int i = 0; i < 4; i++) {
            int idx = tid + i * 256;
            if (TA) {
                int kk = idx / BM, mm = idx % BM;
                As[kk][mm] = cvt(A[(long long)(k0 + kk) * lda + (m0 + mm)]);
            } else {
                int mm = idx / BK, kk = idx % BK;
                As[kk][mm] = cvt(A[(long long)(m0 + mm) * lda + (k0 + kk)]);
            }
        }
#pragma unroll
        for (int i = 0; i < 4; i++) {
            int idx = tid + i * 256;
            if (TB) {
                int nn = idx / BK, kk = idx % BK;
                Bs[kk][nn] = cvt(B[(long long)(n0 + nn) * ldb + (k0 + kk)]);
            } else {
                int kk = idx / BN, nn = idx % BN;
                Bs[kk][nn] = cvt(B[(long long)(k0 + kk) * ldb + (n0 + nn)]);
            }
        }
        __syncthreads();
#pragma unroll
        for (int kk = 0; kk < BK; kk++) {
            float a[4], bb[4];
#pragma unroll
            for (int i = 0; i < 4; i++) a[i] = As[kk][tm + i];
#pragma unroll
            for (int j = 0; j < 4; j++) bb[j] = Bs[kk][tn + j];
#pragma unroll
            for (int i = 0; i < 4; i++)
#pragma unroll
                for (int j = 0; j < 4; j++) acc[i][j] += a[i] * bb[j];
        }
        __syncthreads();
    }
#pragma unroll
    for (int i = 0; i < 4; i++) {
        int m = m0 + tm + i;
#pragma unroll
        for (int j = 0; j < 4; j++) {
            int n = n0 + tn + j;
            float v = acc[i][j] * alpha;
            if (bias) v += bias[n];
            if (residual) v += residual[(long long)m * ldr + n];
            if (gelu_flag) v = 0.5f * v * (1.0f + erff(v * 0.70710678118654752440f));
            stc(&C[(long long)m * ldc + n], v);
        }
    }
}

extern "C" void kernel_launch(void* const* d_in, const int* in_sizes, int n_in,
                              void* d_out, int out_size, void* d_ws, size_t ws_size,
                              hipStream_t stream) {
    const float* x = (const float*)d_in[0];
    const float* context = (const float*)d_in[1];
    // d_in[2] mask, d_in[3] context_mask: all-True constants -> no-op.
    const float* gx = (const float*)d_in[4];
    const float* bx = (const float*)d_in[5];
    const float* gc = (const float*)d_in[6];
    const float* bc = (const float*)d_in[7];
    const float* w_qk = (const float*)d_in[8];
    const float* w_cqk = (const float*)d_in[9];
    const float* w_v = (const float*)d_in[10];
    const float* w_cv = (const float*)d_in[11];
    const float* w_out = (const float*)d_in[12];
    const float* b_out = (const float*)d_in[13];
    const float* w_cout = (const float*)d_in[14];
    const float* b_cout = (const float*)d_in[15];
    const float* w_th = (const float*)d_in[16];
    const float* w_cth = (const float*)d_in[17];
    const float* ffg = (const float*)d_in[18];
    const float* ffb = (const float*)d_in[19];
    const float* ffw1 = (const float*)d_in[20];
    const float* ffb1 = (const float*)d_in[21];
    const float* ffw2 = (const float*)d_in[22];
    const float* ffb2 = (const float*)d_in[23];
    const float* cffg = (const float*)d_in[24];
    const float* cffb = (const float*)d_in[25];
    const float* cffw1 = (const float*)d_in[26];
    const float* cffb1 = (const float*)d_in[27];
    const float* cffw2 = (const float*)d_in[28];
    const float* cffb2 = (const float*)d_in[29];

    const long long TOK = (long long)BB * NN;   // 4096
    const long long NM = (long long)NN * MM;    // 4 M

    // ---- workspace layout (all bf16 activations): ~109.3 MB total ----
    bf16* xn = (bf16*)d_ws;               // 4096*1024
    bf16* cn = xn + TOK * DIMD;           // 4096*1024
    bf16* qk = cn + TOK * DIMD;           // 4096*512
    bf16* vv = qk + TOK * INNERD;
    bf16* cqk = vv + TOK * INNERD;
    bf16* cv = cqk + TOK * INNERD;
    bf16* outb = cv + TOK * INNERD;
    bf16* coutb = outb + TOK * INNERD;
    bf16* sim = coutb + TOK * INNERD;     // 8*NM bf16; reused as FFN hidden (4096*8192 bf16)
    float* stats = (float*)(sim + (long long)HH * NM);
    float* mr = stats;            // 8*2048
    float* lr = mr + HH * 2048;
    float* mc = lr + HH * 2048;
    float* lc = mc + HH * 2048;

    float* out_x = (float*)d_out;
    float* out_c = out_x + TOK * DIMD;

    dim3 blk(256);

    // --- input layernorms ---
    layernorm_k<<<TOK, blk, 0, stream>>>(x, xn, gx, bx);
    layernorm_k<<<TOK, blk, 0, stream>>>(context, cn, gc, bc);

    // --- projections (4096x1024)@(1024x512) -> bf16 ---
    {
        dim3 g(INNERD / 64, TOK / 64, 1);
        gemm_k<float, bf16, false, false><<<g, blk, 0, stream>>>(xn, w_qk, qk,
            TOK, INNERD, DIMD, DIMD, INNERD, INNERD, 0, 0, 0, 1.f, nullptr, nullptr, 0, 0, 0);
        gemm_k<float, bf16, false, false><<<g, blk, 0, stream>>>(xn, w_v, vv,
            TOK, INNERD, DIMD, DIMD, INNERD, INNERD, 0, 0, 0, 1.f, nullptr, nullptr, 0, 0, 0);
        gemm_k<float, bf16, false, false><<<g, blk, 0, stream>>>(cn, w_cqk, cqk,
            TOK, INNERD, DIMD, DIMD, INNERD, INNERD, 0, 0, 0, 1.f, nullptr, nullptr, 0, 0, 0);
        gemm_k<float, bf16, false, false><<<g, blk, 0, stream>>>(cn, w_cv, cv,
            TOK, INNERD, DIMD, DIMD, INNERD, INNERD, 0, 0, 0, 1.f, nullptr, nullptr, 0, 0, 0);
    }

    // --- attention per batch; sim recomputed for the column-softmax path ---
    for (int b = 0; b < BB; b++) {
        const bf16* qk_b = qk + (long long)b * NN * INNERD;
        const bf16* cqk_b = cqk + (long long)b * NN * INNERD;
        const bf16* v_b = vv + (long long)b * NN * INNERD;
        const bf16* cv_b = cv + (long long)b * NN * INNERD;
        bf16* out_b = outb + (long long)b * NN * INNERD;
        bf16* cout_b = coutb + (long long)b * NN * INNERD;

        dim3 gs(MM / 64, NN / 64, HH);
        // sim[h,i,j] = SCALE * qk[i,h,:] . cqk[j,h,:]
        gemm_k<bf16, bf16, false, true><<<gs, blk, 0, stream>>>(qk_b, cqk_b, sim,
            NN, MM, DHD, INNERD, INNERD, MM, DHD, DHD, NM, SCALE_QK, nullptr, nullptr, 0, 0, 0);
        // row softmax (over j) -> mixed by w_th, in place
        rowstats_k<<<HH * NN, blk, 0, stream>>>(sim, mr, lr);
        mixnorm_k<false><<<NM / 256, blk, 0, stream>>>(sim, w_th, mr, lr);
        // out = P @ cv
        {
            dim3 g(1, NN / 64, HH);
            gemm_k<bf16, bf16, false, false><<<g, blk, 0, stream>>>(sim, cv_b, out_b,
                NN, DHD, MM, MM, INNERD, INNERD, NM, DHD, DHD, 1.f, nullptr, nullptr, 0, 0, 0);
        }
        // recompute sim (cheap: K=64), then column path
        gemm_k<bf16, bf16, false, true><<<gs, blk, 0, stream>>>(qk_b, cqk_b, sim,
            NN, MM, DHD, INNERD, INNERD, MM, DHD, DHD, NM, SCALE_QK, nullptr, nullptr, 0, 0, 0);
        {
            dim3 g(MM / 256, HH);
            colstats_k<<<g, blk, 0, stream>>>(sim, mc, lc);
        }
        mixnorm_k<true><<<NM / 256, blk, 0, stream>>>(sim, w_cth, mc, lc);
        // cout[j,:] = sum_i P[i,j] * v[i,:]
        {
            dim3 g(1, MM / 64, HH);
            gemm_k<bf16, bf16, true, false><<<g, blk, 0, stream>>>(sim, v_b, cout_b,
                MM, DHD, NN, MM, INNERD, INNERD, NM, DHD, DHD, 1.f, nullptr, nullptr, 0, 0, 0);
        }
    }

    // --- output projections + bias + residual -> fp32 d_out ---
    {
        dim3 g(DIMD / 64, TOK / 64, 1);
        gemm_k<float, float, false, false><<<g, blk, 0, stream>>>(outb, w_out, out_x,
            TOK, DIMD, INNERD, INNERD, DIMD, DIMD, 0, 0, 0, 1.f, b_out, x, 0, DIMD, 0);
        gemm_k<float, float, false, false><<<g, blk, 0, stream>>>(coutb, w_cout, out_c,
            TOK, DIMD, INNERD, INNERD, DIMD, DIMD, 0, 0, 0, 1.f, b_cout, context, 0, DIMD, 0);
    }

    // --- FFN (x): LN -> gemm1(+gelu) -> gemm2(+residual) ---
    bf16* lnb = xn;           // reuse
    bf16* hid = sim;          // reuse (4096*8192 bf16 = 8*NM bf16 exactly)
    layernorm_k<<<TOK, blk, 0, stream>>>(out_x, lnb, ffg, ffb);
    {
        dim3 g(FFD / 64, TOK / 64, 1);
        gemm_k<float, bf16, false, false><<<g, blk, 0, stream>>>(lnb, ffw1, hid,
            TOK, FFD, DIMD, DIMD, FFD, FFD, 0, 0, 0, 1.f, ffb1, nullptr, 0, 0, 1);
    }
    {
        dim3 g(DIMD / 64, TOK / 64, 1);
        gemm_k<float, float, false, false><<<g, blk, 0, stream>>>(hid, ffw2, out_x,
            TOK, DIMD, FFD, FFD, DIMD, DIMD, 0, 0, 0, 1.f, ffb2, out_x, 0, DIMD, 0);
    }

    // --- FFN (context) ---
    layernorm_k<<<TOK, blk, 0, stream>>>(out_c, lnb, cffg, cffb);
    {
        dim3 g(FFD / 64, TOK / 64, 1);
        gemm_k<float, bf16, false, false><<<g, blk, 0, stream>>>(lnb, cffw1, hid,
            TOK, FFD, DIMD, DIMD, FFD, FFD, 0, 0, 0, 1.f, cffb1, nullptr, 0, 0, 1);
    }
    {
        dim3 g(DIMD / 64, TOK / 64, 1);
        gemm_k<float, float, false, false><<<g, blk, 0, stream>>>(hid, cffw2, out_c,
            TOK, DIMD, FFD, FFD, DIMD, DIMD, 0, 0, 0, 1.f, cffb2, out_c, 0, DIMD, 0);
    }
}

// Round 3
// 1872.201 us; speedup vs baseline: 4.1383x; 4.1383x over previous
//
#include <hip/hip_runtime.h>
#include <hip/hip_bf16.h>
#include <math.h>

#define BB 2
#define NN 2048
#define MM 2048
#define DIMD 1024
#define HH 8
#define DHD 64
#define INNERD 512
#define FFD 8192
#define SCALE_QK 0.125f

typedef __hip_bfloat16 bf16;
typedef float f32x4 __attribute__((ext_vector_type(4)));
typedef short short8 __attribute__((ext_vector_type(8)));

__device__ __forceinline__ float cvt(float v) { return v; }
__device__ __forceinline__ float cvt(bf16 v) { return __bfloat162float(v); }
__device__ __forceinline__ void stc(float* p, float v) { *p = v; }
__device__ __forceinline__ void stc(bf16* p, float v) { *p = __float2bfloat16(v); }

__device__ __forceinline__ void gl_lds16(const bf16* g, bf16* l) {
    __builtin_amdgcn_global_load_lds(
        (const __attribute__((address_space(1))) void*)(g),
        (__attribute__((address_space(3))) void*)(l), 16, 0, 0);
}

// ---------------- reductions ----------------
__device__ __forceinline__ float block_reduce_sum(float v) {
    __shared__ float sh[4];
    int tid = threadIdx.x;
#pragma unroll
    for (int off = 32; off > 0; off >>= 1) v += __shfl_down(v, off, 64);
    __syncthreads();
    if ((tid & 63) == 0) sh[tid >> 6] = v;
    __syncthreads();
    return sh[0] + sh[1] + sh[2] + sh[3];
}

__device__ __forceinline__ float block_reduce_max(float v) {
    __shared__ float sh[4];
    int tid = threadIdx.x;
#pragma unroll
    for (int off = 32; off > 0; off >>= 1) v = fmaxf(v, __shfl_down(v, off, 64));
    __syncthreads();
    if ((tid & 63) == 0) sh[tid >> 6] = v;
    __syncthreads();
    return fmaxf(fmaxf(sh[0], sh[1]), fmaxf(sh[2], sh[3]));
}

// ---------------- layernorm: fp32 in -> bf16 out ----------------
__global__ __launch_bounds__(256) void layernorm_k(const float* __restrict__ in,
                                                   bf16* __restrict__ out,
                                                   const float* __restrict__ g,
                                                   const float* __restrict__ b) {
    long long row = blockIdx.x;
    const float* xr = in + row * DIMD;
    bf16* yr = out + row * DIMD;
    int tid = threadIdx.x;
    float s = 0.f;
    for (int i = tid; i < DIMD; i += 256) s += xr[i];
    float mean = block_reduce_sum(s) * (1.0f / DIMD);
    float s2 = 0.f;
    for (int i = tid; i < DIMD; i += 256) { float d = xr[i] - mean; s2 += d * d; }
    float var = block_reduce_sum(s2) * (1.0f / DIMD);
    float inv = 1.0f / sqrtf(var + 1e-5f);
    for (int i = tid; i < DIMD; i += 256)
        yr[i] = __float2bfloat16((xr[i] - mean) * inv * g[i] + b[i]);
}

// ---------------- transpose + convert: in [R][C] -> out bf16 [C][R] ----------------
template <typename TI>
__global__ __launch_bounds__(256) void transpose_k(const TI* __restrict__ in,
                                                   bf16* __restrict__ out,
                                                   int R, int C) {
    __shared__ bf16 t[32][33];
    int bc = blockIdx.x * 32, br = blockIdx.y * 32;
    int tid = threadIdx.x;
    int c = tid & 31, r0 = tid >> 5;
#pragma unroll
    for (int s = 0; s < 4; s++) {
        int r = r0 + s * 8;
        t[r][c] = __float2bfloat16(cvt(in[(long long)(br + r) * C + bc + c]));
    }
    __syncthreads();
#pragma unroll
    for (int s = 0; s < 4; s++) {
        int r = r0 + s * 8;  // output row within 32-block of C-dim
        out[(long long)(bc + r) * R + br + c] = t[c][r];
    }
}

// ---------------- row softmax stats over j ----------------
__global__ __launch_bounds__(256) void rowstats_k(const bf16* __restrict__ sim,
                                                  float* __restrict__ mr,
                                                  float* __restrict__ lr) {
    long long row = blockIdx.x;  // h*NN + i
    const bf16* xr = sim + row * MM;
    int tid = threadIdx.x;
    float m = -3.4e38f;
    for (int j = tid; j < MM; j += 256) m = fmaxf(m, cvt(xr[j]));
    m = block_reduce_max(m);
    float s = 0.f;
    for (int j = tid; j < MM; j += 256) s += expf(cvt(xr[j]) - m);
    s = block_reduce_sum(s);
    if (tid == 0) { mr[row] = m; lr[row] = s; }
}

// ---------------- col softmax stats over i: partial then combine ----------------
__global__ __launch_bounds__(256) void colstats_part_k(const bf16* __restrict__ sim,
                                                       float* __restrict__ mcp,
                                                       float* __restrict__ lcp) {
    int j = blockIdx.x * 256 + threadIdx.x;
    int h = blockIdx.y;
    int ic = blockIdx.z;
    const bf16* base = sim + (long long)h * NN * MM;
    float m = -3.4e38f, s = 0.f;
    for (int i = ic * 256; i < ic * 256 + 256; i++) {
        float v = cvt(base[(long long)i * MM + j]);
        float nm = fmaxf(m, v);
        s = s * expf(m - nm) + expf(v - nm);
        m = nm;
    }
    mcp[((long long)ic * HH + h) * MM + j] = m;
    lcp[((long long)ic * HH + h) * MM + j] = s;
}

__global__ __launch_bounds__(256) void colstats_comb_k(const float* __restrict__ mcp,
                                                       const float* __restrict__ lcp,
                                                       float* __restrict__ mc,
                                                       float* __restrict__ lc) {
    int idx = blockIdx.x * 256 + threadIdx.x;  // h*MM + j
    int h = idx >> 11, j = idx & (MM - 1);
    float m = -3.4e38f;
#pragma unroll
    for (int ic = 0; ic < 8; ic++) m = fmaxf(m, mcp[((long long)ic * HH + h) * MM + j]);
    float l = 0.f;
#pragma unroll
    for (int ic = 0; ic < 8; ic++)
        l += lcp[((long long)ic * HH + h) * MM + j] * expf(mcp[((long long)ic * HH + h) * MM + j] - m);
    mc[idx] = m;
    lc[idx] = l;
}

// ---------------- row path: normalize + talking-heads mix, in place ----------------
__global__ __launch_bounds__(256) void mixrow_k(bf16* __restrict__ sim,
                                                const float* __restrict__ w,
                                                const float* __restrict__ mr,
                                                const float* __restrict__ lr) {
    __shared__ float ws_[64];
    if (threadIdx.x < 64) ws_[threadIdx.x] = w[threadIdx.x];
    __syncthreads();
    const long long NM = (long long)NN * MM;
    long long idx = (long long)blockIdx.x * 256 + threadIdx.x;
    int si = (int)(idx >> 11);  // i
    float p[HH];
#pragma unroll
    for (int h = 0; h < HH; h++) {
        int st = h * NN + si;
        p[h] = expf(cvt(sim[h * NM + idx]) - mr[st]) * (1.0f / lr[st]);
    }
#pragma unroll
    for (int g = 0; g < HH; g++) {
        float o = 0.f;
#pragma unroll
        for (int h = 0; h < HH; h++) o += ws_[g * 8 + h] * p[h];
        sim[g * NM + idx] = __float2bfloat16(o);
    }
}

// ---------------- col path: normalize + mix + in-place transpose (tile pairs) ----------------
__global__ __launch_bounds__(256) void mixcolT_k(bf16* __restrict__ sim,
                                                 const float* __restrict__ w,
                                                 const float* __restrict__ mc,
                                                 const float* __restrict__ lc) {
    __shared__ bf16 tA[HH][32][34];
    __shared__ bf16 tB[HH][32][34];
    __shared__ float ws_[64];
    const long long NM = (long long)NN * MM;
    int idx = blockIdx.x;
    int I = 0, rem = idx;
    while (rem >= 64 - I) { rem -= 64 - I; I++; }
    int J = I + rem;
    int tid = threadIdx.x;
    if (tid < 64) ws_[tid] = w[tid];
    int jj = tid & 31, i0 = tid >> 5;
#pragma unroll
    for (int h = 0; h < HH; h++) {
#pragma unroll
        for (int s = 0; s < 4; s++) {
            int ii = i0 + s * 8;
            tA[h][ii][jj] = sim[h * NM + (long long)(I * 32 + ii) * MM + J * 32 + jj];
            if (I != J)
                tB[h][ii][jj] = sim[h * NM + (long long)(J * 32 + ii) * MM + I * 32 + jj];
        }
    }
    __syncthreads();
    int il = tid & 31, j0 = tid >> 5;
    // process tA: global (i = I*32+il, j = J*32+jl) -> write plane g at [j][i]
#pragma unroll
    for (int s = 0; s < 4; s++) {
        int jl = j0 + s * 8;
        int jg = J * 32 + jl;
        float p[HH];
#pragma unroll
        for (int h = 0; h < HH; h++)
            p[h] = expf(cvt(tA[h][il][jl]) - mc[h * MM + jg]) * (1.0f / lc[h * MM + jg]);
#pragma unroll
        for (int g = 0; g < HH; g++) {
            float o = 0.f;
#pragma unroll
            for (int h = 0; h < HH; h++) o += ws_[g * 8 + h] * p[h];
            sim[g * NM + (long long)jg * MM + I * 32 + il] = __float2bfloat16(o);
        }
    }
    if (I != J) {
#pragma unroll
        for (int s = 0; s < 4; s++) {
            int jl = j0 + s * 8;
            int jg = I * 32 + jl;  // tB's global j
            float p[HH];
#pragma unroll
            for (int h = 0; h < HH; h++)
                p[h] = expf(cvt(tB[h][il][jl]) - mc[h * MM + jg]) * (1.0f / lc[h * MM + jg]);
#pragma unroll
            for (int g = 0; g < HH; g++) {
                float o = 0.f;
#pragma unroll
                for (int h = 0; h < HH; h++) o += ws_[g * 8 + h] * p[h];
                sim[g * NM + (long long)jg * MM + J * 32 + il] = __float2bfloat16(o);
            }
        }
    }
}

// ---------------- MFMA bf16 GEMM (m97 structure) ----------------
// C[m,n] = alpha * sum_k A[m][k] * B[n][k]  (+bias[n]) (+residual[m,n]) (->gelu)
// A: bf16 [M][K] lda; B: bf16 [N][K] ldb (pre-transposed weights); C: CT.
template <int BM, int BN, int WROWS, typename CT>
__global__ __launch_bounds__(256) void mgemm(
    const bf16* __restrict__ A, const bf16* __restrict__ B, CT* __restrict__ C,
    int K, int lda, int ldb, int ldc,
    long long sA, long long sB, long long sC,
    float alpha, const float* __restrict__ bias,
    const float* __restrict__ residual, long long sR, int ldr, int gelu_flag) {
    constexpr int BK = 32;
    constexpr int WCOLS = 4 / WROWS;
    constexpr int WM = BM / WROWS, WN = BN / WCOLS;
    constexpr int FM = WM / 16, FN = WN / 16;
    constexpr int ACH = BM * BK / 8;  // 16B chunks in A tile
    constexpr int BCH = BN * BK / 8;
    __shared__ bf16 As[BM * BK];
    __shared__ bf16 Bs[BN * BK];
    int z = blockIdx.z;
    A += z * sA;
    B += z * sB;
    C += z * sC;
    if (residual) residual += z * sR;
    int m0 = blockIdx.y * BM, n0 = blockIdx.x * BN;
    int tid = threadIdx.x, lane = tid & 63, w = tid >> 6;
    int wm = (w / WCOLS) * WM, wn = (w % WCOLS) * WN;
    f32x4 acc[FM][FN] = {};
    for (int k0 = 0; k0 < K; k0 += BK) {
        __syncthreads();
#pragma unroll
        for (int c = tid; c < ACH; c += 256) {
            int row = c >> 2, col = (c & 3) * 8;
            gl_lds16(A + (long long)(m0 + row) * lda + k0 + col, As + c * 8);
        }
#pragma unroll
        for (int c = tid; c < BCH; c += 256) {
            int row = c >> 2, col = (c & 3) * 8;
            gl_lds16(B + (long long)(n0 + row) * ldb + k0 + col, Bs + c * 8);
        }
        __syncthreads();
        short8 af[FM], bf[FN];
#pragma unroll
        for (int fm = 0; fm < FM; fm++)
            af[fm] = *(const short8*)&As[(wm + fm * 16 + (lane & 15)) * BK + (lane >> 4) * 8];
#pragma unroll
        for (int fn = 0; fn < FN; fn++)
            bf[fn] = *(const short8*)&Bs[(wn + fn * 16 + (lane & 15)) * BK + (lane >> 4) * 8];
#pragma unroll
        for (int fm = 0; fm < FM; fm++)
#pragma unroll
            for (int fn = 0; fn < FN; fn++)
                acc[fm][fn] = __builtin_amdgcn_mfma_f32_16x16x32_bf16(af[fm], bf[fn], acc[fm][fn], 0, 0, 0);
    }
    // epilogue: C/D layout col=lane&15, row=(lane>>4)*4+reg
#pragma unroll
    for (int fm = 0; fm < FM; fm++) {
#pragma unroll
        for (int fn = 0; fn < FN; fn++) {
#pragma unroll
            for (int r = 0; r < 4; r++) {
                int m = m0 + wm + fm * 16 + (lane >> 4) * 4 + r;
                int n = n0 + wn + fn * 16 + (lane & 15);
                float v = acc[fm][fn][r] * alpha;
                if (bias) v += bias[n];
                if (residual) v += residual[(long long)m * ldr + n];
                if (gelu_flag) v = 0.5f * v * (1.0f + erff(v * 0.70710678118654752440f));
                stc(&C[(long long)m * ldc + n], v);
            }
        }
    }
}

extern "C" void kernel_launch(void* const* d_in, const int* in_sizes, int n_in,
                              void* d_out, int out_size, void* d_ws, size_t ws_size,
                              hipStream_t stream) {
    const float* x = (const float*)d_in[0];
    const float* context = (const float*)d_in[1];
    const float* gx = (const float*)d_in[4];
    const float* bx = (const float*)d_in[5];
    const float* gc = (const float*)d_in[6];
    const float* bc = (const float*)d_in[7];
    const float* w_qk = (const float*)d_in[8];
    const float* w_cqk = (const float*)d_in[9];
    const float* w_v = (const float*)d_in[10];
    const float* w_cv = (const float*)d_in[11];
    const float* w_out = (const float*)d_in[12];
    const float* b_out = (const float*)d_in[13];
    const float* w_cout = (const float*)d_in[14];
    const float* b_cout = (const float*)d_in[15];
    const float* w_th = (const float*)d_in[16];
    const float* w_cth = (const float*)d_in[17];
    const float* ffg = (const float*)d_in[18];
    const float* ffb = (const float*)d_in[19];
    const float* ffw1 = (const float*)d_in[20];
    const float* ffb1 = (const float*)d_in[21];
    const float* ffw2 = (const float*)d_in[22];
    const float* ffb2 = (const float*)d_in[23];
    const float* cffg = (const float*)d_in[24];
    const float* cffb = (const float*)d_in[25];
    const float* cffw1 = (const float*)d_in[26];
    const float* cffb1 = (const float*)d_in[27];
    const float* cffw2 = (const float*)d_in[28];
    const float* cffb2 = (const float*)d_in[29];

    const long long TOK = (long long)BB * NN;   // 4096
    const long long NM = (long long)NN * MM;    // 4 M

    // ---- workspace layout ----
    bf16* xn = (bf16*)d_ws;               // 4096*1024
    bf16* cn = xn + TOK * DIMD;
    bf16* qk = cn + TOK * DIMD;           // 4096*512 (qk, vv adjacent for batched proj)
    bf16* vv = qk + TOK * INNERD;
    bf16* cqk = vv + TOK * INNERD;
    bf16* cv = cqk + TOK * INNERD;
    bf16* outb = cv + TOK * INNERD;
    bf16* coutb = outb + TOK * INNERD;
    bf16* sim = coutb + TOK * INNERD;     // 8*NM; reused as FFN hidden [4096][8192]
    bf16* wT = sim + (long long)HH * NM;  // transposed bf16 weights
    bf16* wqkT = wT;                           // [512][1024]
    bf16* wvT = wqkT + (long long)INNERD * DIMD;
    bf16* wcqkT = wvT + (long long)INNERD * DIMD;
    bf16* wcvT = wcqkT + (long long)INNERD * DIMD;
    bf16* woutT = wcvT + (long long)INNERD * DIMD;    // [1024][512]
    bf16* wcoutT = woutT + (long long)DIMD * INNERD;
    bf16* ffw1T = wcoutT + (long long)DIMD * INNERD;  // [8192][1024]
    bf16* ffw2T = ffw1T + (long long)FFD * DIMD;      // [1024][8192]
    bf16* cffw1T = ffw2T + (long long)DIMD * FFD;
    bf16* cffw2T = cffw1T + (long long)FFD * DIMD;
    bf16* vT = cffw2T + (long long)DIMD * FFD;        // [512][2048] per current batch
    bf16* cvT = vT + (long long)INNERD * NN;
    float* stats = (float*)(cvT + (long long)INNERD * NN);
    float* mr = stats;                 // 8*2048
    float* lr = mr + HH * NN;
    float* mc = lr + HH * NN;
    float* lc = mc + HH * MM;
    float* mcp = lc + HH * MM;         // 8*8*2048
    float* lcp = mcp + 8 * HH * MM;

    float* out_x = (float*)d_out;
    float* out_c = out_x + TOK * DIMD;

    dim3 blk(256);

    // --- weight convert+transpose (fp32 [K][N] -> bf16 [N][K]) ---
    transpose_k<float><<<dim3(INNERD / 32, DIMD / 32), blk, 0, stream>>>(w_qk, wqkT, DIMD, INNERD);
    transpose_k<float><<<dim3(INNERD / 32, DIMD / 32), blk, 0, stream>>>(w_v, wvT, DIMD, INNERD);
    transpose_k<float><<<dim3(INNERD / 32, DIMD / 32), blk, 0, stream>>>(w_cqk, wcqkT, DIMD, INNERD);
    transpose_k<float><<<dim3(INNERD / 32, DIMD / 32), blk, 0, stream>>>(w_cv, wcvT, DIMD, INNERD);
    transpose_k<float><<<dim3(DIMD / 32, INNERD / 32), blk, 0, stream>>>(w_out, woutT, INNERD, DIMD);
    transpose_k<float><<<dim3(DIMD / 32, INNERD / 32), blk, 0, stream>>>(w_cout, wcoutT, INNERD, DIMD);
    transpose_k<float><<<dim3(FFD / 32, DIMD / 32), blk, 0, stream>>>(ffw1, ffw1T, DIMD, FFD);
    transpose_k<float><<<dim3(DIMD / 32, FFD / 32), blk, 0, stream>>>(ffw2, ffw2T, FFD, DIMD);
    transpose_k<float><<<dim3(FFD / 32, DIMD / 32), blk, 0, stream>>>(cffw1, cffw1T, DIMD, FFD);
    transpose_k<float><<<dim3(DIMD / 32, FFD / 32), blk, 0, stream>>>(cffw2, cffw2T, FFD, DIMD);

    // --- input layernorms ---
    layernorm_k<<<TOK, blk, 0, stream>>>(x, xn, gx, bx);
    layernorm_k<<<TOK, blk, 0, stream>>>(context, cn, gc, bc);

    // --- projections, batched over {qk,v} and {cqk,cv} (z=2) ---
    {
        dim3 g(INNERD / 128, TOK / 128, 2);
        mgemm<128, 128, 2, bf16><<<g, blk, 0, stream>>>(xn, wqkT, qk,
            DIMD, DIMD, DIMD, INNERD,
            0, (long long)INNERD * DIMD, TOK * INNERD,
            1.f, nullptr, nullptr, 0, 0, 0);
        mgemm<128, 128, 2, bf16><<<g, blk, 0, stream>>>(cn, wcqkT, cqk,
            DIMD, DIMD, DIMD, INNERD,
            0, (long long)INNERD * DIMD, TOK * INNERD,
            1.f, nullptr, nullptr, 0, 0, 0);
    }

    // --- attention, per batch ---
    for (int b = 0; b < BB; b++) {
        const bf16* qk_b = qk + (long long)b * NN * INNERD;
        const bf16* cqk_b = cqk + (long long)b * NN * INNERD;
        const bf16* v_b = vv + (long long)b * NN * INNERD;
        const bf16* cv_b = cv + (long long)b * NN * INNERD;
        bf16* out_b = outb + (long long)b * NN * INNERD;
        bf16* cout_b = coutb + (long long)b * NN * INNERD;

        // transposes of v, cv: [2048][512] -> [512][2048]
        transpose_k<bf16><<<dim3(INNERD / 32, NN / 32), blk, 0, stream>>>(v_b, vT, NN, INNERD);
        transpose_k<bf16><<<dim3(INNERD / 32, NN / 32), blk, 0, stream>>>(cv_b, cvT, NN, INNERD);

        // sim[h,i,j] = SCALE * qk_h[i,:] . cqk_h[j,:]   (z = head)
        dim3 gs(MM / 128, NN / 128, HH);
        mgemm<128, 128, 2, bf16><<<gs, blk, 0, stream>>>(qk_b, cqk_b, sim,
            DHD, INNERD, INNERD, MM, 64, 64, NM, SCALE_QK, nullptr, nullptr, 0, 0, 0);

        // row softmax -> mix (in place)
        rowstats_k<<<HH * NN, blk, 0, stream>>>(sim, mr, lr);
        mixrow_k<<<NM / 256, blk, 0, stream>>>(sim, w_th, mr, lr);
        // out = P @ cv   (A = P plane h, B = cvT head rows)
        {
            dim3 g(1, NN / 128, HH);
            mgemm<128, 64, 4, bf16><<<g, blk, 0, stream>>>(sim, cvT, out_b,
                MM, MM, NN, INNERD, NM, (long long)DHD * NN, 64,
                1.f, nullptr, nullptr, 0, 0, 0);
        }

        // recompute sim, column path
        mgemm<128, 128, 2, bf16><<<gs, blk, 0, stream>>>(qk_b, cqk_b, sim,
            DHD, INNERD, INNERD, MM, 64, 64, NM, SCALE_QK, nullptr, nullptr, 0, 0, 0);
        {
            dim3 g(MM / 256, HH, 8);
            colstats_part_k<<<g, blk, 0, stream>>>(sim, mcp, lcp);
        }
        colstats_comb_k<<<HH * MM / 256, blk, 0, stream>>>(mcp, lcp, mc, lc);
        mixcolT_k<<<64 * 65 / 2, blk, 0, stream>>>(sim, w_cth, mc, lc);
        // cout = PcT @ v  (A = PcT plane g [j][i], B = vT head rows [d][i])
        {
            dim3 g(1, MM / 128, HH);
            mgemm<128, 64, 4, bf16><<<g, blk, 0, stream>>>(sim, vT, cout_b,
                NN, MM, NN, INNERD, NM, (long long)DHD * NN, 64,
                1.f, nullptr, nullptr, 0, 0, 0);
        }
    }

    // --- output projections + bias + residual -> fp32 d_out ---
    {
        dim3 g(DIMD / 128, TOK / 128, 1);
        mgemm<128, 128, 2, float><<<g, blk, 0, stream>>>(outb, woutT, out_x,
            INNERD, INNERD, INNERD, DIMD, 0, 0, 0, 1.f, b_out, x, 0, DIMD, 0);
        mgemm<128, 128, 2, float><<<g, blk, 0, stream>>>(coutb, wcoutT, out_c,
            INNERD, INNERD, INNERD, DIMD, 0, 0, 0, 1.f, b_cout, context, 0, DIMD, 0);
    }

    // --- FFN (x) ---
    bf16* lnb = xn;
    bf16* hid = sim;  // [4096][8192]
    layernorm_k<<<TOK, blk, 0, stream>>>(out_x, lnb, ffg, ffb);
    {
        dim3 g(FFD / 128, TOK / 128, 1);
        mgemm<128, 128, 2, bf16><<<g, blk, 0, stream>>>(lnb, ffw1T, hid,
            DIMD, DIMD, DIMD, FFD, 0, 0, 0, 1.f, ffb1, nullptr, 0, 0, 1);
    }
    {
        dim3 g(DIMD / 128, TOK / 128, 1);
        mgemm<128, 128, 2, float><<<g, blk, 0, stream>>>(hid, ffw2T, out_x,
            FFD, FFD, FFD, DIMD, 0, 0, 0, 1.f, ffb2, out_x, 0, DIMD, 0);
    }

    // --- FFN (context) ---
    layernorm_k<<<TOK, blk, 0, stream>>>(out_c, lnb, cffg, cffb);
    {
        dim3 g(FFD / 128, TOK / 128, 1);
        mgemm<128, 128, 2, bf16><<<g, blk, 0, stream>>>(lnb, cffw1T, hid,
            DIMD, DIMD, DIMD, FFD, 0, 0, 0, 1.f, cffb1, nullptr, 0, 0, 1);
    }
    {
        dim3 g(DIMD / 128, TOK / 128, 1);
        mgemm<128, 128, 2, float><<<g, blk, 0, stream>>>(hid, cffw2T, out_c,
            FFD, FFD, FFD, DIMD, 0, 0, 0, 1.f, cffb2, out_c, 0, DIMD, 0);
    }
}

// Round 4
// 1555.494 us; speedup vs baseline: 4.9808x; 1.2036x over previous
//
#include <hip/hip_runtime.h>
#include <hip/hip_bf16.h>
#include <math.h>

#define BB 2
#define NN 2048
#define MM 2048
#define DIMD 1024
#define HH 8
#define DHD 64
#define INNERD 512
#define FFD 8192
#define SCALE_QK 0.125f

typedef __hip_bfloat16 bf16;
typedef float f32x4 __attribute__((ext_vector_type(4)));
typedef short short8 __attribute__((ext_vector_type(8)));
static const long long NM = (long long)NN * MM;

__device__ __forceinline__ float cvt(float v) { return v; }
__device__ __forceinline__ float cvt(bf16 v) { return __bfloat162float(v); }
__device__ __forceinline__ void stc(float* p, float v) { *p = v; }
__device__ __forceinline__ void stc(bf16* p, float v) { *p = __float2bfloat16(v); }

__device__ __forceinline__ void gl_lds16(const bf16* g, bf16* l) {
    __builtin_amdgcn_global_load_lds(
        (const __attribute__((address_space(1))) void*)(g),
        (__attribute__((address_space(3))) void*)(l), 16, 0, 0);
}

// ---------------- reductions ----------------
__device__ __forceinline__ float block_reduce_sum(float v) {
    __shared__ float sh[4];
    int tid = threadIdx.x;
#pragma unroll
    for (int off = 32; off > 0; off >>= 1) v += __shfl_down(v, off, 64);
    __syncthreads();
    if ((tid & 63) == 0) sh[tid >> 6] = v;
    __syncthreads();
    return sh[0] + sh[1] + sh[2] + sh[3];
}

__device__ __forceinline__ float block_reduce_max(float v) {
    __shared__ float sh[4];
    int tid = threadIdx.x;
#pragma unroll
    for (int off = 32; off > 0; off >>= 1) v = fmaxf(v, __shfl_down(v, off, 64));
    __syncthreads();
    if ((tid & 63) == 0) sh[tid >> 6] = v;
    __syncthreads();
    return fmaxf(fmaxf(sh[0], sh[1]), fmaxf(sh[2], sh[3]));
}

// ---------------- layernorm: fp32 in -> bf16 out ----------------
__global__ __launch_bounds__(256) void layernorm_k(const float* __restrict__ in,
                                                   bf16* __restrict__ out,
                                                   const float* __restrict__ g,
                                                   const float* __restrict__ b) {
    long long row = blockIdx.x;
    const float* xr = in + row * DIMD;
    bf16* yr = out + row * DIMD;
    int tid = threadIdx.x;
    float s = 0.f;
    for (int i = tid; i < DIMD; i += 256) s += xr[i];
    float mean = block_reduce_sum(s) * (1.0f / DIMD);
    float s2 = 0.f;
    for (int i = tid; i < DIMD; i += 256) { float d = xr[i] - mean; s2 += d * d; }
    float var = block_reduce_sum(s2) * (1.0f / DIMD);
    float inv = 1.0f / sqrtf(var + 1e-5f);
    for (int i = tid; i < DIMD; i += 256)
        yr[i] = __float2bfloat16((xr[i] - mean) * inv * g[i] + b[i]);
}

// ---------------- bias add (fp32, vectorized) ----------------
__global__ __launch_bounds__(256) void biasadd_k(float* __restrict__ out,
                                                 const float* __restrict__ bias) {
    long long idx = (long long)blockIdx.x * 256 + threadIdx.x;  // float4 index
    f32x4 v = ((f32x4*)out)[idx];
    const f32x4 bv = ((const f32x4*)bias)[idx & (DIMD / 4 - 1)];
    v.x += bv.x; v.y += bv.y; v.z += bv.z; v.w += bv.w;
    ((f32x4*)out)[idx] = v;
}

// ---------------- transpose + convert: in [R][C] -> out bf16 [C][R] ----------------
template <typename TI>
__global__ __launch_bounds__(256) void transpose_k(const TI* __restrict__ in,
                                                   bf16* __restrict__ out,
                                                   int R, int C) {
    __shared__ bf16 t[32][33];
    int bc = blockIdx.x * 32, br = blockIdx.y * 32;
    int tid = threadIdx.x;
    int c = tid & 31, r0 = tid >> 5;
#pragma unroll
    for (int s = 0; s < 4; s++) {
        int r = r0 + s * 8;
        t[r][c] = __float2bfloat16(cvt(in[(long long)(br + r) * C + bc + c]));
    }
    __syncthreads();
#pragma unroll
    for (int s = 0; s < 4; s++) {
        int r = r0 + s * 8;
        out[(long long)(bc + r) * R + br + c] = t[c][r];
    }
}

// ---------------- col softmax stats over i: partial then combine ----------------
__global__ __launch_bounds__(256) void colstats_part_k(const bf16* __restrict__ sim,
                                                       float* __restrict__ mcp,
                                                       float* __restrict__ lcp) {
    int j = blockIdx.x * 256 + threadIdx.x;
    int h = blockIdx.y;
    int ic = blockIdx.z;
    const bf16* base = sim + (long long)h * NM;
    float m = -3.4e38f, s = 0.f;
    for (int i = ic * 256; i < ic * 256 + 256; i++) {
        float v = cvt(base[(long long)i * MM + j]);
        float nm = fmaxf(m, v);
        s = s * expf(m - nm) + expf(v - nm);
        m = nm;
    }
    mcp[((long long)ic * HH + h) * MM + j] = m;
    lcp[((long long)ic * HH + h) * MM + j] = s;
}

__global__ __launch_bounds__(256) void colstats_comb_k(const float* __restrict__ mcp,
                                                       const float* __restrict__ lcp,
                                                       float* __restrict__ mc,
                                                       float* __restrict__ lc) {
    int idx = blockIdx.x * 256 + threadIdx.x;  // h*MM + j
    int h = idx >> 11, j = idx & (MM - 1);
    float m = -3.4e38f;
#pragma unroll
    for (int ic = 0; ic < 8; ic++) m = fmaxf(m, mcp[((long long)ic * HH + h) * MM + j]);
    float l = 0.f;
#pragma unroll
    for (int ic = 0; ic < 8; ic++)
        l += lcp[((long long)ic * HH + h) * MM + j] * expf(mcp[((long long)ic * HH + h) * MM + j] - m);
    mc[idx] = m;
    lc[idx] = l;
}

// ---------------- col path: normalize + mix + transpose, sim -> simT ----------------
__global__ __launch_bounds__(256) void mixcolT_k(const bf16* __restrict__ sim,
                                                 bf16* __restrict__ simT,
                                                 const float* __restrict__ w,
                                                 const float* __restrict__ mc,
                                                 const float* __restrict__ lc) {
    __shared__ bf16 t[HH][32][33];
    __shared__ float ws_[64];
    int j0 = blockIdx.x * 32, i0 = blockIdx.y * 32;
    int tid = threadIdx.x;
    if (tid < 64) ws_[tid] = w[tid];
    int jj = tid & 31, r0 = tid >> 5;
#pragma unroll
    for (int h = 0; h < HH; h++)
#pragma unroll
        for (int s = 0; s < 4; s++) {
            int ii = r0 + s * 8;
            t[h][ii][jj] = sim[h * NM + (long long)(i0 + ii) * MM + j0 + jj];
        }
    __syncthreads();
    int il = tid & 31, c0 = tid >> 5;
#pragma unroll
    for (int s = 0; s < 4; s++) {
        int jl = c0 + s * 8;
        int jg = j0 + jl;
        float p[HH];
#pragma unroll
        for (int h = 0; h < HH; h++)
            p[h] = expf(cvt(t[h][il][jl]) - mc[h * MM + jg]) * (1.0f / lc[h * MM + jg]);
#pragma unroll
        for (int g = 0; g < HH; g++) {
            float o = 0.f;
#pragma unroll
            for (int h = 0; h < HH; h++) o += ws_[g * 8 + h] * p[h];
            simT[g * NM + (long long)jg * MM + i0 + il] = __float2bfloat16(o);
        }
    }
}

// ---------------- row path: fused row-stats + normalize + mix, in place ----------------
__global__ __launch_bounds__(256) void rowsoftmix_k(bf16* __restrict__ sim,
                                                    const float* __restrict__ w) {
    __shared__ float ws_[64];
    int i = blockIdx.x, tid = threadIdx.x;
    if (tid < 64) ws_[tid] = w[tid];
    float v[HH][8];
#pragma unroll
    for (int h = 0; h < HH; h++)
#pragma unroll
        for (int c = 0; c < 8; c++)
            v[h][c] = cvt(sim[h * NM + (long long)i * MM + tid + c * 256]);
    float mh[HH], lh[HH];
#pragma unroll
    for (int h = 0; h < HH; h++) {
        float m = v[h][0];
#pragma unroll
        for (int c = 1; c < 8; c++) m = fmaxf(m, v[h][c]);
        mh[h] = block_reduce_max(m);
    }
#pragma unroll
    for (int h = 0; h < HH; h++) {
        float s = 0.f;
#pragma unroll
        for (int c = 0; c < 8; c++) s += expf(v[h][c] - mh[h]);
        lh[h] = 1.0f / block_reduce_sum(s);
    }
    __syncthreads();
#pragma unroll
    for (int c = 0; c < 8; c++) {
        float p[HH];
#pragma unroll
        for (int h = 0; h < HH; h++) p[h] = expf(v[h][c] - mh[h]) * lh[h];
#pragma unroll
        for (int g = 0; g < HH; g++) {
            float o = 0.f;
#pragma unroll
            for (int h = 0; h < HH; h++) o += ws_[g * 8 + h] * p[h];
            sim[g * NM + (long long)i * MM + tid + c * 256] = __float2bfloat16(o);
        }
    }
}

// ---------------- MFMA bf16 GEMM ----------------
// C[m,n] = alpha * sum_k A[m][k] * B[n][k]  (+bias[n]) (+residual[m,n]) (->gelu)
// ZMODE: 0 linear (A+=z*sA)  1 AHALF (A+=(z>>1)*sA)  2 ROWGAP (outb [b][2] interleave;
//        z selects bias2/residual2)
template <int BM, int BN, int WROWS, int ZMODE, bool ATOMIC, typename CT>
__global__ __launch_bounds__(256) void mgemm(
    const bf16* __restrict__ A, const bf16* __restrict__ B, CT* __restrict__ C,
    int K, int lda, int ldb, int ldc,
    long long sA, long long sB, long long sC,
    float alpha, const float* __restrict__ bias, const float* __restrict__ bias2,
    const float* __restrict__ residual, const float* __restrict__ residual2,
    int ldr, int gelu_flag) {
    constexpr int BK = 32;
    constexpr int WCOLS = 4 / WROWS;
    constexpr int WM = BM / WROWS, WN = BN / WCOLS;
    constexpr int FM = WM / 16, FN = WN / 16;
    constexpr int ACH = BM * BK / 8;
    constexpr int BCH = BN * BK / 8;
    __shared__ bf16 As[BM * BK];
    __shared__ bf16 Bs[BN * BK];
    int z = blockIdx.z;
    int m0 = blockIdx.y * BM, n0 = blockIdx.x * BN;
    if (ZMODE == 0) A += z * sA;
    else if (ZMODE == 1) A += (long long)(z >> 1) * sA;
    else if (ZMODE == 2) A += ((long long)(((m0 >> 11) << 1) + z) * 2048 - m0) * lda;
    B += z * sB;
    C += z * sC;
    const float* bb_ = bias;
    const float* rr_ = residual;
    if (ZMODE == 2 && z) { bb_ = bias2; rr_ = residual2; }
    int tid = threadIdx.x, lane = tid & 63, w = tid >> 6;
    int wm = (w / WCOLS) * WM, wn = (w % WCOLS) * WN;
    f32x4 acc[FM][FN] = {};
    for (int k0 = 0; k0 < K; k0 += BK) {
        __syncthreads();
#pragma unroll
        for (int c = tid; c < ACH; c += 256) {
            int row = c >> 2, col = (c & 3) * 8;
            gl_lds16(A + (long long)(m0 + row) * lda + k0 + col, As + c * 8);
        }
#pragma unroll
        for (int c = tid; c < BCH; c += 256) {
            int row = c >> 2, col = (c & 3) * 8;
            gl_lds16(B + (long long)(n0 + row) * ldb + k0 + col, Bs + c * 8);
        }
        __syncthreads();
        short8 af[FM], bfr[FN];
#pragma unroll
        for (int fm = 0; fm < FM; fm++)
            af[fm] = *(const short8*)&As[(wm + fm * 16 + (lane & 15)) * BK + (lane >> 4) * 8];
#pragma unroll
        for (int fn = 0; fn < FN; fn++)
            bfr[fn] = *(const short8*)&Bs[(wn + fn * 16 + (lane & 15)) * BK + (lane >> 4) * 8];
#pragma unroll
        for (int fm = 0; fm < FM; fm++)
#pragma unroll
            for (int fn = 0; fn < FN; fn++)
                acc[fm][fn] = __builtin_amdgcn_mfma_f32_16x16x32_bf16(af[fm], bfr[fn], acc[fm][fn], 0, 0, 0);
    }
#pragma unroll
    for (int fm = 0; fm < FM; fm++) {
#pragma unroll
        for (int fn = 0; fn < FN; fn++) {
#pragma unroll
            for (int r = 0; r < 4; r++) {
                int m = m0 + wm + fm * 16 + (lane >> 4) * 4 + r;
                int n = n0 + wn + fn * 16 + (lane & 15);
                float v = acc[fm][fn][r] * alpha;
                if (bb_) v += bb_[n];
                if (rr_) v += rr_[(long long)m * ldr + n];
                if (gelu_flag) v = 0.5f * v * (1.0f + erff(v * 0.70710678118654752440f));
                if (ATOMIC) atomicAdd((float*)&C[(long long)m * ldc + n], v);
                else stc(&C[(long long)m * ldc + n], v);
            }
        }
    }
}

// ---------------- attention P@V, both paths in one launch ----------------
// z in [0,16): h = z&7, sel = z>>3. A = P + z*NM (lda=MM); B = Vt + z*DHD*NN (ldb=NN);
// C = O + sel*NN*INNERD + h*DHD (ldc=INNERD). K = 2048.
__global__ __launch_bounds__(256) void pv_k(const bf16* __restrict__ P,
                                            const bf16* __restrict__ Vt,
                                            bf16* __restrict__ O) {
    constexpr int BK = 32;
    __shared__ bf16 As[64 * BK];
    __shared__ bf16 Bs[64 * BK];
    int z = blockIdx.z;
    int h = z & 7, sel = z >> 3;
    const bf16* A = P + (long long)z * NM;
    const bf16* B = Vt + (long long)z * DHD * NN;
    bf16* C = O + (long long)sel * NN * INNERD + h * DHD;
    int m0 = blockIdx.y * 64;
    int tid = threadIdx.x, lane = tid & 63, w = tid >> 6;
    int wm = w * 16;
    f32x4 acc[4] = {};
    for (int k0 = 0; k0 < NN; k0 += BK) {
        __syncthreads();
        {
            int row = tid >> 2, col = (tid & 3) * 8;
            gl_lds16(A + (long long)(m0 + row) * MM + k0 + col, As + tid * 8);
            gl_lds16(B + (long long)row * NN + k0 + col, Bs + tid * 8);
        }
        __syncthreads();
        short8 af = *(const short8*)&As[(wm + (lane & 15)) * BK + (lane >> 4) * 8];
#pragma unroll
        for (int fn = 0; fn < 4; fn++) {
            short8 bfr = *(const short8*)&Bs[(fn * 16 + (lane & 15)) * BK + (lane >> 4) * 8];
            acc[fn] = __builtin_amdgcn_mfma_f32_16x16x32_bf16(af, bfr, acc[fn], 0, 0, 0);
        }
    }
#pragma unroll
    for (int fn = 0; fn < 4; fn++)
#pragma unroll
        for (int r = 0; r < 4; r++) {
            int m = m0 + wm + (lane >> 4) * 4 + r;
            int n = fn * 16 + (lane & 15);
            stc(&C[(long long)m * INNERD + n], acc[fn][r]);
        }
}

extern "C" void kernel_launch(void* const* d_in, const int* in_sizes, int n_in,
                              void* d_out, int out_size, void* d_ws, size_t ws_size,
                              hipStream_t stream) {
    const float* x = (const float*)d_in[0];
    const float* context = (const float*)d_in[1];
    const float* gx = (const float*)d_in[4];
    const float* bx = (const float*)d_in[5];
    const float* gc = (const float*)d_in[6];
    const float* bc = (const float*)d_in[7];
    const float* w_qk = (const float*)d_in[8];
    const float* w_cqk = (const float*)d_in[9];
    const float* w_v = (const float*)d_in[10];
    const float* w_cv = (const float*)d_in[11];
    const float* w_out = (const float*)d_in[12];
    const float* b_out = (const float*)d_in[13];
    const float* w_cout = (const float*)d_in[14];
    const float* b_cout = (const float*)d_in[15];
    const float* w_th = (const float*)d_in[16];
    const float* w_cth = (const float*)d_in[17];
    const float* ffg = (const float*)d_in[18];
    const float* ffb = (const float*)d_in[19];
    const float* ffw1 = (const float*)d_in[20];
    const float* ffb1 = (const float*)d_in[21];
    const float* ffw2 = (const float*)d_in[22];
    const float* ffb2 = (const float*)d_in[23];
    const float* cffg = (const float*)d_in[24];
    const float* cffb = (const float*)d_in[25];
    const float* cffw1 = (const float*)d_in[26];
    const float* cffb1 = (const float*)d_in[27];
    const float* cffw2 = (const float*)d_in[28];
    const float* cffb2 = (const float*)d_in[29];

    const long long TOK = (long long)BB * NN;   // 4096

    // ---- workspace layout (~180 MB) ----
    bf16* xn = (bf16*)d_ws;                       // 4 M elems
    bf16* cn = xn + TOK * DIMD;                   // 4 M (right after xn: AHALF)
    bf16* qk = cn + TOK * DIMD;                   // 2 M each, order qk,vv,cqk,cv
    bf16* vv = qk + TOK * INNERD;
    bf16* cqk = vv + TOK * INNERD;
    bf16* cv = cqk + TOK * INNERD;
    bf16* outb = cv + TOK * INNERD;               // [B][2][NN][INNERD] = 4 M
    bf16* sim = outb + (long long)BB * 2 * NN * INNERD;  // 32 M (8 planes)
    bf16* w4 = sim + (long long)HH * NM;          // 32 M: simT during attention;
    bf16* ffw1T = w4;                             //   then ffw1T,cffw1T,ffw2T,cffw2T
    bf16* cffw1T = ffw1T + (long long)FFD * DIMD;
    bf16* ffw2T = cffw1T + (long long)FFD * DIMD;
    bf16* cffw2T = ffw2T + (long long)DIMD * FFD;
    bf16* simT = w4;                              // alias (attention phase only)
    bf16* wqkT = w4 + 4LL * FFD * DIMD;           // 0.5 M each, order for proj z
    bf16* wvT = wqkT + (long long)INNERD * DIMD;
    bf16* wcqkT = wvT + (long long)INNERD * DIMD;
    bf16* wcvT = wcqkT + (long long)INNERD * DIMD;
    bf16* woutT = wcvT + (long long)INNERD * DIMD;
    bf16* wcoutT = woutT + (long long)DIMD * INNERD;
    bf16* cvT = wcoutT + (long long)DIMD * INNERD;  // order cvT then vT for pv z-map
    bf16* vT = cvT + (long long)INNERD * NN;
    float* stats = (float*)(vT + (long long)INNERD * NN);
    float* mc = stats;                 // 8*2048
    float* lc = mc + HH * MM;
    float* mcp = lc + HH * MM;         // 8*8*2048
    float* lcp = mcp + 8 * HH * MM;

    float* out_x = (float*)d_out;
    float* out_c = out_x + TOK * DIMD;

    dim3 blk(256);

    // --- small weight transposes (proj + out-proj) ---
    transpose_k<float><<<dim3(INNERD / 32, DIMD / 32), blk, 0, stream>>>(w_qk, wqkT, DIMD, INNERD);
    transpose_k<float><<<dim3(INNERD / 32, DIMD / 32), blk, 0, stream>>>(w_v, wvT, DIMD, INNERD);
    transpose_k<float><<<dim3(INNERD / 32, DIMD / 32), blk, 0, stream>>>(w_cqk, wcqkT, DIMD, INNERD);
    transpose_k<float><<<dim3(INNERD / 32, DIMD / 32), blk, 0, stream>>>(w_cv, wcvT, DIMD, INNERD);
    transpose_k<float><<<dim3(DIMD / 32, INNERD / 32), blk, 0, stream>>>(w_out, woutT, INNERD, DIMD);
    transpose_k<float><<<dim3(DIMD / 32, INNERD / 32), blk, 0, stream>>>(w_cout, wcoutT, INNERD, DIMD);

    // --- input layernorms ---
    layernorm_k<<<TOK, blk, 0, stream>>>(x, xn, gx, bx);
    layernorm_k<<<TOK, blk, 0, stream>>>(context, cn, gc, bc);

    // --- all 4 projections in one launch (z=4, AHALF) ---
    {
        dim3 g(INNERD / 128, TOK / 128, 4);
        mgemm<128, 128, 2, 1, false, bf16><<<g, blk, 0, stream>>>(xn, wqkT, qk,
            DIMD, DIMD, DIMD, INNERD,
            TOK * DIMD, (long long)INNERD * DIMD, TOK * INNERD,
            1.f, nullptr, nullptr, nullptr, nullptr, 0, 0);
    }

    // --- attention, per batch ---
    for (int b = 0; b < BB; b++) {
        const bf16* qk_b = qk + (long long)b * NN * INNERD;
        const bf16* cqk_b = cqk + (long long)b * NN * INNERD;
        const bf16* v_b = vv + (long long)b * NN * INNERD;
        const bf16* cv_b = cv + (long long)b * NN * INNERD;
        bf16* outb_b = outb + (long long)b * 2 * NN * INNERD;

        transpose_k<bf16><<<dim3(INNERD / 32, NN / 32), blk, 0, stream>>>(cv_b, cvT, NN, INNERD);
        transpose_k<bf16><<<dim3(INNERD / 32, NN / 32), blk, 0, stream>>>(v_b, vT, NN, INNERD);

        // sim[h,i,j] = SCALE * qk_h[i,:] . cqk_h[j,:]
        {
            dim3 gs(MM / 128, NN / 128, HH);
            mgemm<128, 128, 2, 0, false, bf16><<<gs, blk, 0, stream>>>(qk_b, cqk_b, sim,
                DHD, INNERD, INNERD, MM, DHD, DHD, NM,
                SCALE_QK, nullptr, nullptr, nullptr, nullptr, 0, 0);
        }
        // column stats from pristine sim
        {
            dim3 g(MM / 256, HH, 8);
            colstats_part_k<<<g, blk, 0, stream>>>(sim, mcp, lcp);
        }
        colstats_comb_k<<<HH * MM / 256, blk, 0, stream>>>(mcp, lcp, mc, lc);
        // col path -> simT (transposed+mixed), then row path in place
        mixcolT_k<<<dim3(MM / 32, NN / 32), blk, 0, stream>>>(sim, simT, w_cth, mc, lc);
        rowsoftmix_k<<<NN, blk, 0, stream>>>(sim, w_th);
        // both P@V products, one launch (z=16)
        pv_k<<<dim3(1, NN / 64, 16), blk, 0, stream>>>(sim, cvT, outb_b);
    }

    // --- out-projections, one launch (z=2, ROWGAP) + bias + residual -> d_out ---
    {
        dim3 g(DIMD / 128, TOK / 128, 2);
        mgemm<128, 128, 2, 2, false, float><<<g, blk, 0, stream>>>(outb, woutT, out_x,
            INNERD, INNERD, INNERD, DIMD,
            0, (long long)DIMD * INNERD, TOK * DIMD,
            1.f, b_out, b_cout, x, context, DIMD, 0);
    }

    // --- FFN weight transposes (w4 region now free) ---
    transpose_k<float><<<dim3(FFD / 32, DIMD / 32), blk, 0, stream>>>(ffw1, ffw1T, DIMD, FFD);
    transpose_k<float><<<dim3(FFD / 32, DIMD / 32), blk, 0, stream>>>(cffw1, cffw1T, DIMD, FFD);
    transpose_k<float><<<dim3(DIMD / 32, FFD / 32), blk, 0, stream>>>(ffw2, ffw2T, FFD, DIMD);
    transpose_k<float><<<dim3(DIMD / 32, FFD / 32), blk, 0, stream>>>(cffw2, cffw2T, FFD, DIMD);

    // --- FFN per model: LN -> bias-preadd -> GEMM1(+gelu) -> split-K GEMM2 (atomic) ---
    const float* g_[2] = {ffg, cffg};
    const float* bterm_[2] = {ffb, cffb};
    const float* b1_[2] = {ffb1, cffb1};
    const float* b2_[2] = {ffb2, cffb2};
    const bf16* w1T_[2] = {ffw1T, cffw1T};
    const bf16* w2T_[2] = {ffw2T, cffw2T};
    float* outp_[2] = {out_x, out_c};
    bf16* lnb = xn;
    bf16* hid = sim;  // [4096][8192]
    for (int m = 0; m < 2; m++) {
        layernorm_k<<<TOK, blk, 0, stream>>>(outp_[m], lnb, g_[m], bterm_[m]);
        biasadd_k<<<TOK * DIMD / 1024, blk, 0, stream>>>(outp_[m], b2_[m]);
        {
            dim3 g(FFD / 128, TOK / 128, 1);
            mgemm<128, 128, 2, 0, false, bf16><<<g, blk, 0, stream>>>(lnb, w1T_[m], hid,
                DIMD, DIMD, DIMD, FFD, 0, 0, 0,
                1.f, b1_[m], nullptr, nullptr, nullptr, 0, 1);
        }
        {
            // split-K=4: z offsets A,B by z*2048 in k; atomicAdd into d_out
            dim3 g(DIMD / 128, TOK / 128, 4);
            mgemm<128, 128, 2, 0, true, float><<<g, blk, 0, stream>>>(hid, w2T_[m], outp_[m],
                FFD / 4, FFD, FFD, DIMD, 2048, 2048, 0,
                1.f, nullptr, nullptr, nullptr, nullptr, 0, 0);
        }
    }
}